// Round 4
// baseline (646.534 us; speedup 1.0000x reference)
//
#include <hip/hip_runtime.h>

// mLSTM block, bf16-MFMA, R8: (1) all weight-prep (8 transposes + Wup
// convert + bcomb) merged into ONE prep_kernel (segmented by blockIdx.x,
// pointers via by-value struct) -- 15 dispatches -> 7, attacking ~150us of
// inter-dispatch dead time. (2) T5 s_setprio(1/0) around MFMA clusters in
// both GEMM kernels (counted-vmcnt role-split schedule -> arbitration has
// room; pre-committed: null = inconclusive).
// R7 algebraic fold retained: x_adj = x_norm @ (W_up@W_adj) + (b_up@W_adj
// + b_adj); W_combT = WadjT @ Wup via gemm_bt<2>.
// Both GEMMs keep the R6 2-deep counted-vmcnt pipeline (never drain vmcnt
// in the main loop).
// Tokens M = 16384, D = 1024, P = 2048, H = 1024.
//
// LDS swizzle (gemm_bt, rows = 64 B = 4 chunks of 16 B): chunk c of row r
// stored at slot c ^ ((r>>1)&3), via swizzled SOURCE address
// (global_load_lds forces dest = base + lane*16). Readers use
// quad ^ ((l15>>1)&3). Measured 0 conflicts.
//
// gemm_gates swizzle (rows = 128 B = 8 chunks of 16 B): slot = c ^ (r&7);
// staging lane covers row lane>>3, slot lane&7, source chunk
// (lane&7)^(lane>>3). Readers use (ks*4+quad)^(l15&7). Measured 0 conflicts.
//
// Workspace (MiB offsets), total 150 MiB:
//   [0,32)    xn -> ht (xn dead after xadj-GEMM) -> y (same-thread r/w alias)
//   [32,34)   WcombT [1024,1024]
//   [36,36+4K) b_comb (f32[1024])
//   [96,128)  xadj
//   [128,132) Wup_bf [1024,2048] (row-major, no transpose)
//   [132,136) WadjT  [1024,2048]
//   [136,148) Wcat   [6*1024,1024] (order q,k,v,i,f,o)
//   [148,150) WdnT   [1024,1024]

typedef unsigned short u16;
typedef __attribute__((ext_vector_type(4))) unsigned short u16x4;
typedef __attribute__((ext_vector_type(8))) unsigned short u16x8;
typedef __attribute__((ext_vector_type(8))) __bf16 bf16x8;
typedef __attribute__((ext_vector_type(4))) float f32x4;

__device__ __forceinline__ float bf2f(u16 u) {
    union { unsigned int i; float f; } c; c.i = ((unsigned int)u) << 16; return c.f;
}
__device__ __forceinline__ u16 f2bf(float f) {
    union { float f; unsigned int i; } c; c.f = f;
    unsigned int lsb = (c.i >> 16) & 1u;
    c.i += 0x7fffu + lsb;                 // round-to-nearest-even
    return (u16)(c.i >> 16);
}
__device__ __forceinline__ float sigmoidf(float z) {
    return 1.0f / (1.0f + __expf(-z));
}

// async global->LDS, 16B per lane; LDS dest = wave-uniform base + lane*16
#define GLDS16(gp, lp)                                                        \
    __builtin_amdgcn_global_load_lds(                                         \
        (__attribute__((address_space(1))) void*)(void*)(gp),                 \
        (__attribute__((address_space(3))) void*)(lp), 16, 0, 0)

#define BM 128
#define BN 128
#define BK 32

// C[M,N] = A[M,K] @ B[K,N] with Bt = B^T stored [N,K], all bf16, fp32 acc.
// MODE 0: out bf16 = (acc + bias[n]) * scale
// MODE 1: out f32  = (acc + bias[n]) * scale + resid[m*N+n]
// MODE 2: out bf16 = acc * scale              (no bias; bias may be nullptr)
template <int MODE>
__global__ __launch_bounds__(256) void gemm_bt(
    const u16* __restrict__ A, const u16* __restrict__ Bt,
    const float* __restrict__ bias, const float* __restrict__ resid,
    void* __restrict__ out, int M, int N, int K, float scale)
{
    __shared__ __align__(16) u16 As[2 * BM * BK];   // 2 x 8 KB
    __shared__ __align__(16) u16 Bs[2 * BN * BK];   // 2 x 8 KB

    const int tid  = threadIdx.x;
    const int lane = tid & 63;
    const int wave = tid >> 6;
    const int l15  = lane & 15;
    const int quad = lane >> 4;

    const long bm = (long)blockIdx.y * BM;
    const long bn = (long)blockIdx.x * BN;
    const int  wm = (wave >> 1) * 64;   // wave's 64x64 quadrant
    const int  wn = (wave & 1) * 64;

    f32x4 acc[4][4] = {};

    // staging: thread tid covers row tid>>2; SOURCE chunk is swizzled so the
    // identity LDS placement (lane*16) realizes the XOR-swizzled layout.
    const int  r0 = tid >> 2;
    const int  ck = (((tid & 3) ^ ((tid >> 3) & 3)) * 8);
    const u16* ga0 = A  + (bm + r0) * (long)K + ck;
    const u16* gb0 = Bt + (bn + r0) * (long)K + ck;
    const int  ldst = wave * 512;        // wave's dest inside a buffer (u16)

    auto stage = [&](int t_, int b_) {
        const long kof = (long)t_ * BK;
        u16* dA = &As[b_ * (BM * BK) + ldst];
        u16* dB = &Bs[b_ * (BN * BK) + ldst];
        GLDS16(ga0 + kof, dA);
        GLDS16(ga0 + kof + 64 * (long)K, dA + 2048);
        GLDS16(gb0 + kof, dB);
        GLDS16(gb0 + kof + 64 * (long)K, dB + 2048);
    };

    const int q8s = (quad ^ ((l15 >> 1) & 3)) * 8;   // swizzled chunk offset
    const int nk  = K / BK;

    stage(0, 0);    // 4 loads
    stage(1, 1);    // 4 loads -> 8 in flight

    for (int t = 0; t < nk; ++t) {
        const int cur = t & 1;
        if (t + 1 < nk) asm volatile("s_waitcnt vmcnt(4)" ::: "memory");
        else            asm volatile("s_waitcnt vmcnt(0)" ::: "memory");
        __builtin_amdgcn_s_barrier();

        bf16x8 af[4], bfr[4];
#pragma unroll
        for (int t4 = 0; t4 < 4; ++t4) {
            af[t4]  = *(const bf16x8*)&As[cur * (BM * BK) + (wm + t4 * 16 + l15) * BK + q8s];
            bfr[t4] = *(const bf16x8*)&Bs[cur * (BN * BK) + (wn + t4 * 16 + l15) * BK + q8s];
        }
        asm volatile("s_waitcnt lgkmcnt(0)" ::: "memory");
        __builtin_amdgcn_s_barrier();
        if (t + 2 < nk) stage(t + 2, cur);

        __builtin_amdgcn_s_setprio(1);
#pragma unroll
        for (int mt = 0; mt < 4; ++mt)
#pragma unroll
            for (int nt = 0; nt < 4; ++nt)
                acc[mt][nt] = __builtin_amdgcn_mfma_f32_16x16x32_bf16(
                    af[mt], bfr[nt], acc[mt][nt], 0, 0, 0);
        __builtin_amdgcn_s_setprio(0);
    }

    // C/D layout: col = lane&15, row = quad*4 + reg
#pragma unroll
    for (int nt = 0; nt < 4; ++nt) {
        const long n  = bn + wn + nt * 16 + l15;
        const float bv = (MODE == 2) ? 0.0f : bias[n];
#pragma unroll
        for (int mt = 0; mt < 4; ++mt) {
            const long m0 = bm + wm + mt * 16 + quad * 4;
#pragma unroll
            for (int r = 0; r < 4; ++r) {
                const long idx = (m0 + r) * N + n;
                const float val = (acc[mt][nt][r] + bv) * scale;
                if (MODE == 1) ((float*)out)[idx] = val + resid[idx];
                else           ((u16*)out)[idx] = f2bf(val);
            }
        }
    }
}

// Fused 6-way gate GEMM + mLSTM gate math.
// A = xadj [M,K], Wcat = 6 gate weights transposed, [6*1024, K] (order
// q,k,v,i,f,o). Block = 128(M) x 32(N) of ALL six projections, BK=64,
// 256 threads / 4 waves. Wave w owns m-half (w>>1)*64 and n-half (w&1)*16:
// per BK-step 8 A-frag reads + 12 B-frag reads feed 48 MFMAs. f32 accs,
// gate math in-register, writes ht bf16 [M,1024]. 2-deep pipelined.
__global__ __launch_bounds__(256) void gemm_gates(
    const u16* __restrict__ A, const u16* __restrict__ Wcat,
    const float* __restrict__ bq_, const float* __restrict__ bk_,
    const float* __restrict__ bv_, const float* __restrict__ bi_,
    const float* __restrict__ bf_, const float* __restrict__ bo_,
    u16* __restrict__ ht, int M, int N, int K)
{
    __shared__ __align__(16) u16 As[2 * 128 * 64];       // 2 x 16 KB
    __shared__ __align__(16) u16 Bs[2 * 6 * 32 * 64];    // 2 x 24 KB

    const int tid  = threadIdx.x;
    const int lane = tid & 63;
    const int wave = tid >> 6;          // 0..3
    const int l15  = lane & 15;
    const int quad = lane >> 4;

    const long bm = (long)blockIdx.y * 128;
    const long bn = (long)blockIdx.x * 32;

    f32x4 acc[6][4] = {};

    // ---- staging: 1 KB wave-chunks of 8 rows (rows are 128 B = 64 u16).
    // lane covers row lane>>3 of the chunk, slot lane&7; source chunk is
    // (lane&7)^(lane>>3) so identity LDS placement realizes slot = c^(r&7).
    const int  rr = lane >> 3;                       // row within 8-row group
    const int  ck = (((lane & 7) ^ rr) * 8);         // swizzled source (u16)

    const u16* gaj[4];                               // A: 16 chunks, 4/wave
    int lAo[4];
#pragma unroll
    for (int j = 0; j < 4; ++j) {
        const int c = wave * 4 + j;                  // chunk 0..15
        gaj[j] = A + (bm + c * 8 + rr) * (long)K + ck;
        lAo[j] = c * 512;
    }
    const u16* gbj[6];                               // B: 24 chunks, 6/wave
    int lBo[6];
#pragma unroll
    for (int j = 0; j < 6; ++j) {
        const int c = wave * 6 + j;                  // chunk 0..23
        const int g = c >> 2;                        // gate
        const int r = (c & 3) * 8 + rr;              // row in gate tile 0..31
        gbj[j] = Wcat + ((long)g * 1024 + bn + r) * (long)K + ck;
        lBo[j] = c * 512;
    }

    auto stage = [&](int t_, int b_) {
        const long kof = (long)t_ * 64;
#pragma unroll
        for (int j = 0; j < 4; ++j)
            GLDS16(gaj[j] + kof, &As[b_ * 8192 + lAo[j]]);
#pragma unroll
        for (int j = 0; j < 6; ++j)
            GLDS16(gbj[j] + kof, &Bs[b_ * 12288 + lBo[j]]);
    };

    const int mh = (wave >> 1) * 64;                 // wave m-half
    const int nb = (wave & 1) * 16;                  // wave n-half
    const int l7 = l15 & 7;
    const int nk = K >> 6;                           // 16

    stage(0, 0);    // 10 loads
    stage(1, 1);    // 10 loads -> 20 in flight

    for (int t = 0; t < nk; ++t) {
        const int cur = t & 1;
        if (t + 1 < nk) asm volatile("s_waitcnt vmcnt(10)" ::: "memory");
        else            asm volatile("s_waitcnt vmcnt(0)"  ::: "memory");
        __builtin_amdgcn_s_barrier();

        const int ab = cur * 8192;     // buffer base (u16), mult of 128 B
        const int bb = cur * 12288;

        // ---- ks = 0: read + MFMA (reads complete before 2nd barrier)
        {
            const int so = (quad ^ l7) * 8;
            bf16x8 af[4];
#pragma unroll
            for (int t4 = 0; t4 < 4; ++t4)
                af[t4] = *(const bf16x8*)&As[ab + (mh + t4 * 16 + l15) * 64 + so];
            __builtin_amdgcn_s_setprio(1);
#pragma unroll
            for (int g = 0; g < 6; ++g) {
                const bf16x8 bfrag =
                    *(const bf16x8*)&Bs[bb + (g * 32 + nb + l15) * 64 + so];
#pragma unroll
                for (int t4 = 0; t4 < 4; ++t4)
                    acc[g][t4] = __builtin_amdgcn_mfma_f32_16x16x32_bf16(
                        af[t4], bfrag, acc[g][t4], 0, 0, 0);
            }
            __builtin_amdgcn_s_setprio(0);
        }
        // ---- ks = 1: reads only, then release the buffer
        bf16x8 af1[4], bf1[6];
        {
            const int so = ((4 + quad) ^ l7) * 8;
#pragma unroll
            for (int t4 = 0; t4 < 4; ++t4)
                af1[t4] = *(const bf16x8*)&As[ab + (mh + t4 * 16 + l15) * 64 + so];
#pragma unroll
            for (int g = 0; g < 6; ++g)
                bf1[g] = *(const bf16x8*)&Bs[bb + (g * 32 + nb + l15) * 64 + so];
        }
        asm volatile("s_waitcnt lgkmcnt(0)" ::: "memory");
        __builtin_amdgcn_s_barrier();
        if (t + 2 < nk) stage(t + 2, cur);

        // ---- ks = 1 MFMAs (cover the just-issued loads)
        __builtin_amdgcn_s_setprio(1);
#pragma unroll
        for (int g = 0; g < 6; ++g)
#pragma unroll
            for (int t4 = 0; t4 < 4; ++t4)
                acc[g][t4] = __builtin_amdgcn_mfma_f32_16x16x32_bf16(
                    af1[t4], bf1[g], acc[g][t4], 0, 0, 0);
        __builtin_amdgcn_s_setprio(0);
    }

    // C/D layout: col = lane&15, row = quad*4 + reg. One n per lane.
    const long n = bn + nb + l15;
    const float bqn = bq_[n], bkn = bk_[n], bvn = bv_[n];
    const float bin = bi_[n], bfn = bf_[n], bon = bo_[n];
#pragma unroll
    for (int t = 0; t < 4; ++t) {
        const long m0 = bm + mh + t * 16 + quad * 4;
#pragma unroll
        for (int r = 0; r < 4; ++r) {
            const float qf = acc[0][t][r] + bqn;
            const float kf = (acc[1][t][r] + bkn) * 0.125f;
            const float vf = acc[2][t][r] + bvn;
            const float fi = acc[3][t][r] + bin;
            const float ff = acc[4][t][r] + bfn;
            const float osig = sigmoidf(acc[5][t][r] + bon);
            const float mx = fmaxf(ff, fi);
            const float fe = __expf(ff - mx);
            const float ct = fe * vf * kf;
            const float h  = osig * (ct * qf) / fmaxf(fabsf(kf * qf), 1.0f);
            ht[(m0 + r) * N + n] = f2bf(h);
        }
    }
}

// LayerNorm over 1024 cols, fp32 in -> bf16 out. One 256-thread block per row.
__global__ __launch_bounds__(256) void ln_in_kernel(
    const float* __restrict__ x, const float* __restrict__ g,
    const float* __restrict__ b, u16* __restrict__ xn)
{
    const long row = blockIdx.x;
    const int  tid = threadIdx.x;
    const float4 v = ((const float4*)(x + row * 1024))[tid];
    float s  = v.x + v.y + v.z + v.w;
    float s2 = v.x * v.x + v.y * v.y + v.z * v.z + v.w * v.w;
#pragma unroll
    for (int off = 32; off > 0; off >>= 1) {
        s  += __shfl_down(s, off);
        s2 += __shfl_down(s2, off);
    }
    __shared__ float red[8];
    const int wave = tid >> 6;
    if ((tid & 63) == 0) { red[wave] = s; red[4 + wave] = s2; }
    __syncthreads();
    if (tid == 0) {
        const float S  = red[0] + red[1] + red[2] + red[3];
        const float S2 = red[4] + red[5] + red[6] + red[7];
        const float mu = S * (1.0f / 1024.0f);
        const float var = S2 * (1.0f / 1024.0f) - mu * mu;
        red[0] = mu; red[1] = rsqrtf(var + 1e-3f);
    }
    __syncthreads();
    const float mu = red[0], rstd = red[1];
    const int c = tid * 4;
    u16x4 o;
    o.x = f2bf((v.x - mu) * rstd * g[c + 0] + b[c + 0]);
    o.y = f2bf((v.y - mu) * rstd * g[c + 1] + b[c + 1]);
    o.z = f2bf((v.z - mu) * rstd * g[c + 2] + b[c + 2]);
    o.w = f2bf((v.w - mu) * rstd * g[c + 3] + b[c + 3]);
    *(u16x4*)(xn + row * 1024 + c) = o;
}

// ---- merged weight-prep -------------------------------------------------
// Segments by blockIdx.x:
//   [0,2048)       WadjT  transpose, K=2048 N=1024 (x=bid&31, y=bid>>5)
//   [2048,8192)    6 gate transposes -> Wcat, K=N=1024, 1024 tiles each
//   [8192,9216)    WdnT   transpose, K=N=1024
//   [9216,11264)   Wup f32->bf16 linear convert (1024 elems/block)
//   [11264,11268)  bcomb[h] = sum_p bup[p]*Wadj[p,h] + badj[h]  (4 blocks)
struct PrepArgs {
    const float *Wadj, *Wq, *Wk, *Wv, *Wi, *Wf, *Wo, *Wdn, *Wup;
    const float *bup, *badj;
    u16 *WadjT, *Wcat, *WdnT, *Wup_bf;
    float *bcomb;
};

__device__ __forceinline__ void do_transpose(
    const float* __restrict__ W, u16* __restrict__ Wt,
    int K, int N, int bx, int by, float (&t)[32][33])
{
    const int tx = threadIdx.x & 31;
    const int ty = threadIdx.x >> 5;
    const long bn = (long)bx * 32;
    const long bk = (long)by * 32;
#pragma unroll
    for (int j = 0; j < 4; ++j)
        t[ty + j * 8][tx] = W[(bk + ty + j * 8) * N + bn + tx];
    __syncthreads();
#pragma unroll
    for (int j = 0; j < 4; ++j)
        Wt[(bn + ty + j * 8) * K + bk + tx] = f2bf(t[tx][ty + j * 8]);
}

__global__ __launch_bounds__(256) void prep_kernel(PrepArgs a)
{
    __shared__ float t[32][33];
    int bid = blockIdx.x;
    if (bid < 2048) {                      // WadjT
        do_transpose(a.Wadj, a.WadjT, 2048, 1024, bid & 31, bid >> 5, t);
        return;
    }
    bid -= 2048;
    if (bid < 6144) {                      // gates -> Wcat (q,k,v,i,f,o)
        const int g = bid >> 10, tt = bid & 1023;
        const float* Wg = g == 0 ? a.Wq : g == 1 ? a.Wk : g == 2 ? a.Wv
                        : g == 3 ? a.Wi : g == 4 ? a.Wf : a.Wo;
        do_transpose(Wg, a.Wcat + (long)g * 1024 * 1024, 1024, 1024,
                     tt & 31, tt >> 5, t);
        return;
    }
    bid -= 6144;
    if (bid < 1024) {                      // WdnT
        do_transpose(a.Wdn, a.WdnT, 1024, 1024, bid & 31, bid >> 5, t);
        return;
    }
    bid -= 1024;
    if (bid < 2048) {                      // Wup convert (no transpose)
        const long i = ((long)bid * 256 + threadIdx.x) * 4;
        const float4 v = *(const float4*)(a.Wup + i);
        u16x4 o;
        o.x = f2bf(v.x); o.y = f2bf(v.y); o.z = f2bf(v.z); o.w = f2bf(v.w);
        *(u16x4*)(a.Wup_bf + i) = o;
        return;
    }
    bid -= 2048;
    {                                      // bcomb (f32, from raw Wadj)
        const int h = bid * 256 + threadIdx.x;
        float s = 0.0f;
#pragma unroll 8
        for (int p = 0; p < 2048; ++p)
            s += a.bup[p] * a.Wadj[(long)p * 1024 + h];
        a.bcomb[h] = s + a.badj[h];
    }
}

// LN2 over ht rows + sigmoid(xadj) product. y may alias ht (same-thread r/w).
__global__ __launch_bounds__(256) void ln2_kernel(
    const u16* __restrict__ ht, const u16* __restrict__ xadj,
    const float* __restrict__ g2, const float* __restrict__ b2,
    u16* __restrict__ y)
{
    const long base = (long)blockIdx.x * 1024;
    const int  tid = threadIdx.x;
    const int  c = tid * 4;
    const u16x4 hv = *(const u16x4*)&ht[base + c];
    const u16x4 xv = *(const u16x4*)&xadj[base + c];

    float h[4];
    float s = 0.0f, s2 = 0.0f;
#pragma unroll
    for (int j = 0; j < 4; ++j) {
        h[j] = bf2f(hv[j]);
        s += h[j]; s2 += h[j] * h[j];
    }
#pragma unroll
    for (int off = 32; off > 0; off >>= 1) {
        s  += __shfl_down(s, off);
        s2 += __shfl_down(s2, off);
    }
    __shared__ float red[8];
    const int wave = tid >> 6;
    if ((tid & 63) == 0) { red[wave] = s; red[4 + wave] = s2; }
    __syncthreads();
    if (tid == 0) {
        const float S  = red[0] + red[1] + red[2] + red[3];
        const float S2 = red[4] + red[5] + red[6] + red[7];
        const float mu = S * (1.0f / 1024.0f);
        const float var = S2 * (1.0f / 1024.0f) - mu * mu;
        red[0] = mu; red[1] = rsqrtf(var + 1e-3f);
    }
    __syncthreads();
    const float mu = red[0], rstd = red[1];
    u16x4 o;
#pragma unroll
    for (int j = 0; j < 4; ++j)
        o[j] = f2bf(((h[j] - mu) * rstd * g2[c + j] + b2[c + j]) * sigmoidf(bf2f(xv[j])));
    *(u16x4*)&y[base + c] = o;
}

extern "C" void kernel_launch(void* const* d_in, const int* in_sizes, int n_in,
                              void* d_out, int out_size, void* d_ws, size_t ws_size,
                              hipStream_t stream)
{
    const float* x    = (const float*)d_in[0];
    const float* g1   = (const float*)d_in[1];
    const float* b1   = (const float*)d_in[2];
    const float* Wup  = (const float*)d_in[3];
    const float* bup  = (const float*)d_in[4];
    const float* Wadj = (const float*)d_in[5];
    const float* badj = (const float*)d_in[6];
    const float* Wq = (const float*)d_in[7];   const float* bq = (const float*)d_in[8];
    const float* Wk = (const float*)d_in[9];   const float* bk = (const float*)d_in[10];
    const float* Wv = (const float*)d_in[11];  const float* bv = (const float*)d_in[12];
    const float* Wi = (const float*)d_in[13];  const float* bi = (const float*)d_in[14];
    const float* Wf = (const float*)d_in[15];  const float* bf = (const float*)d_in[16];
    const float* Wo = (const float*)d_in[17];  const float* bo = (const float*)d_in[18];
    const float* g2 = (const float*)d_in[19];  const float* b2 = (const float*)d_in[20];
    const float* Wdn = (const float*)d_in[21]; const float* bdn = (const float*)d_in[22];

    const int M = 8 * 2048;     // 16384 tokens
    const int D = 1024, P = 2048, H = 1024;

    char* ws = (char*)d_ws;
    const size_t MB = 1024 * 1024;
    u16* xn     = (u16*)(ws + 0);
    u16* htb    = (u16*)(ws + 0);          // reuse xn (dead after xadj-GEMM)
    u16* yb     = (u16*)(ws + 0);          // alias ht (same-thread read-then-write)
    u16* WcombT = (u16*)(ws + 32 * MB);    // [1024,1024] 2MB
    float* bcomb = (float*)(ws + 36 * MB); // f32[1024]
    u16* xadj   = (u16*)(ws + 96 * MB);
    u16* Wup_bf = (u16*)(ws + 128 * MB);   // [1024,2048] row-major 4MB
    u16* WadjT  = (u16*)(ws + 132 * MB);   // [1024,2048] 4MB
    u16* Wcat   = (u16*)(ws + 136 * MB);   // [6*1024,1024] 12MB, q,k,v,i,f,o
    u16* WdnT   = (u16*)(ws + 148 * MB);   // [1024,1024] 2MB -> ends at 150 MiB

    // 1) LN1
    ln_in_kernel<<<M, 256, 0, stream>>>(x, g1, b1, xn);

    // 2) all weight prep in one dispatch
    PrepArgs pa;
    pa.Wadj = Wadj; pa.Wq = Wq; pa.Wk = Wk; pa.Wv = Wv; pa.Wi = Wi;
    pa.Wf = Wf; pa.Wo = Wo; pa.Wdn = Wdn; pa.Wup = Wup;
    pa.bup = bup; pa.badj = badj;
    pa.WadjT = WadjT; pa.Wcat = Wcat; pa.WdnT = WdnT; pa.Wup_bf = Wup_bf;
    pa.bcomb = bcomb;
    prep_kernel<<<11268, 256, 0, stream>>>(pa);

    // 3) W_combT = WadjT @ Wup_bf  ([H,P] @ [P,D] -> [H,D], i.e. (Wup@Wadj)^T)
    gemm_bt<2><<<dim3(D / BN, H / BM), 256, 0, stream>>>(
        WadjT, Wup_bf, nullptr, nullptr, WcombT, H, D, P, 1.0f);

    // 4) xadj = xn @ W_comb + b_comb   (folded up+adj projection)
    gemm_bt<0><<<dim3(H / BN, M / BM), 256, 0, stream>>>(
        xn, WcombT, bcomb, nullptr, xadj, M, H, D, 1.0f);

    // 5) fused six-gate GEMM + gate math -> ht (128M x 32N x 6g, BK=64)
    gemm_gates<<<dim3(H / 32, M / 128), 256, 0, stream>>>(
        xadj, Wcat, bq, bk, bv, bi, bf, bo, htb, M, H, H);

    // 6) LN2 + sigmoid(xadj) -> y
    ln2_kernel<<<M, 256, 0, stream>>>(htb, xadj, g2, b2, yb);

    // 7) down-proj + bias + residual, fp32 out
    gemm_bt<1><<<dim3(D / BN, M / BM), 256, 0, stream>>>(yb, WdnT, bdn, x, (float*)d_out, M, D, H, 1.0f);
}

// Round 5
// 580.701 us; speedup vs baseline: 1.1134x; 1.1134x over previous
//
#include <hip/hip_runtime.h>

// mLSTM block, bf16-MFMA, R9:
//  - REVERT R8's setprio (null-to-negative, matches m190) and R8's serial
//    bcomb tail (4-block serial dot gated the whole prep dispatch).
//  - prep_kernel keeps the merged transposes/convert (parallelism preserved);
//    bcomb back to its own parallel 1024-block kernel (reads WadjT).
//  - gemm_gates restructured to m201-style HALF-TILE staging: 4 rotating
//    half-buffers (32 K-cols each, same 80 KB LDS total). Per phase:
//    vmcnt(10) counted wait -> bar -> 10 ds_read_b128 -> lgkm(0) -> bar ->
//    stage half s+3 (5 loads) -> 24 MFMA. Loads issue evenly (5/phase,
//    no 10-load burst), prefetch 1.5 tiles, vmcnt never drained mid-loop.
//    Staged buffer (s+3)&3 == (s-1)&3 is past all reads (phase s-1's
//    lgkm+bar). Rows are 64 B -> reuses gemm_bt's proven 0-conflict
//    4-chunk XOR swizzle for BOTH staging and fragment reads.
//    K-accumulation order unchanged -> bit-identical numerics.
// R7 algebraic fold retained: x_adj = x_norm @ (W_up@W_adj) + (b_up@W_adj
// + b_adj); W_combT = WadjT @ Wup via gemm_bt<2>.
// Tokens M = 16384, D = 1024, P = 2048, H = 1024.
//
// LDS swizzle (64 B rows = 4 chunks of 16 B): chunk c of row r stored at
// slot c ^ ((r>>1)&3), realized by swizzling the SOURCE address
// (global_load_lds forces dest = base + lane*16). Readers use
// quad ^ ((l15>>1)&3); all row offsets are multiples of 16 so only l15
// matters. Measured 0 conflicts.
//
// Workspace (MiB offsets), total 150 MiB:
//   [0,32)    xn -> ht (xn dead after xadj-GEMM) -> y (same-thread r/w alias)
//   [32,34)   WcombT [1024,1024]
//   [36,36+4K) b_comb (f32[1024])
//   [96,128)  xadj
//   [128,132) Wup_bf [1024,2048] (row-major, no transpose)
//   [132,136) WadjT  [1024,2048]
//   [136,148) Wcat   [6*1024,1024] (order q,k,v,i,f,o)
//   [148,150) WdnT   [1024,1024]

typedef unsigned short u16;
typedef __attribute__((ext_vector_type(4))) unsigned short u16x4;
typedef __attribute__((ext_vector_type(8))) unsigned short u16x8;
typedef __attribute__((ext_vector_type(8))) __bf16 bf16x8;
typedef __attribute__((ext_vector_type(4))) float f32x4;

__device__ __forceinline__ float bf2f(u16 u) {
    union { unsigned int i; float f; } c; c.i = ((unsigned int)u) << 16; return c.f;
}
__device__ __forceinline__ u16 f2bf(float f) {
    union { float f; unsigned int i; } c; c.f = f;
    unsigned int lsb = (c.i >> 16) & 1u;
    c.i += 0x7fffu + lsb;                 // round-to-nearest-even
    return (u16)(c.i >> 16);
}
__device__ __forceinline__ float sigmoidf(float z) {
    return 1.0f / (1.0f + __expf(-z));
}

// async global->LDS, 16B per lane; LDS dest = wave-uniform base + lane*16
#define GLDS16(gp, lp)                                                        \
    __builtin_amdgcn_global_load_lds(                                         \
        (__attribute__((address_space(1))) void*)(void*)(gp),                 \
        (__attribute__((address_space(3))) void*)(lp), 16, 0, 0)

#define BM 128
#define BN 128
#define BK 32

// C[M,N] = A[M,K] @ B[K,N] with Bt = B^T stored [N,K], all bf16, fp32 acc.
// MODE 0: out bf16 = (acc + bias[n]) * scale
// MODE 1: out f32  = (acc + bias[n]) * scale + resid[m*N+n]
// MODE 2: out bf16 = acc * scale              (no bias; bias may be nullptr)
template <int MODE>
__global__ __launch_bounds__(256) void gemm_bt(
    const u16* __restrict__ A, const u16* __restrict__ Bt,
    const float* __restrict__ bias, const float* __restrict__ resid,
    void* __restrict__ out, int M, int N, int K, float scale)
{
    __shared__ __align__(16) u16 As[2 * BM * BK];   // 2 x 8 KB
    __shared__ __align__(16) u16 Bs[2 * BN * BK];   // 2 x 8 KB

    const int tid  = threadIdx.x;
    const int lane = tid & 63;
    const int wave = tid >> 6;
    const int l15  = lane & 15;
    const int quad = lane >> 4;

    const long bm = (long)blockIdx.y * BM;
    const long bn = (long)blockIdx.x * BN;
    const int  wm = (wave >> 1) * 64;   // wave's 64x64 quadrant
    const int  wn = (wave & 1) * 64;

    f32x4 acc[4][4] = {};

    // staging: thread tid covers row tid>>2; SOURCE chunk is swizzled so the
    // identity LDS placement (lane*16) realizes the XOR-swizzled layout.
    const int  r0 = tid >> 2;
    const int  ck = (((tid & 3) ^ ((tid >> 3) & 3)) * 8);
    const u16* ga0 = A  + (bm + r0) * (long)K + ck;
    const u16* gb0 = Bt + (bn + r0) * (long)K + ck;
    const int  ldst = wave * 512;        // wave's dest inside a buffer (u16)

    auto stage = [&](int t_, int b_) {
        const long kof = (long)t_ * BK;
        u16* dA = &As[b_ * (BM * BK) + ldst];
        u16* dB = &Bs[b_ * (BN * BK) + ldst];
        GLDS16(ga0 + kof, dA);
        GLDS16(ga0 + kof + 64 * (long)K, dA + 2048);
        GLDS16(gb0 + kof, dB);
        GLDS16(gb0 + kof + 64 * (long)K, dB + 2048);
    };

    const int q8s = (quad ^ ((l15 >> 1) & 3)) * 8;   // swizzled chunk offset
    const int nk  = K / BK;

    stage(0, 0);    // 4 loads
    stage(1, 1);    // 4 loads -> 8 in flight

    for (int t = 0; t < nk; ++t) {
        const int cur = t & 1;
        if (t + 1 < nk) asm volatile("s_waitcnt vmcnt(4)" ::: "memory");
        else            asm volatile("s_waitcnt vmcnt(0)" ::: "memory");
        __builtin_amdgcn_s_barrier();

        bf16x8 af[4], bfr[4];
#pragma unroll
        for (int t4 = 0; t4 < 4; ++t4) {
            af[t4]  = *(const bf16x8*)&As[cur * (BM * BK) + (wm + t4 * 16 + l15) * BK + q8s];
            bfr[t4] = *(const bf16x8*)&Bs[cur * (BN * BK) + (wn + t4 * 16 + l15) * BK + q8s];
        }
        asm volatile("s_waitcnt lgkmcnt(0)" ::: "memory");
        __builtin_amdgcn_s_barrier();
        if (t + 2 < nk) stage(t + 2, cur);

#pragma unroll
        for (int mt = 0; mt < 4; ++mt)
#pragma unroll
            for (int nt = 0; nt < 4; ++nt)
                acc[mt][nt] = __builtin_amdgcn_mfma_f32_16x16x32_bf16(
                    af[mt], bfr[nt], acc[mt][nt], 0, 0, 0);
    }

    // C/D layout: col = lane&15, row = quad*4 + reg
#pragma unroll
    for (int nt = 0; nt < 4; ++nt) {
        const long n  = bn + wn + nt * 16 + l15;
        const float bv = (MODE == 2) ? 0.0f : bias[n];
#pragma unroll
        for (int mt = 0; mt < 4; ++mt) {
            const long m0 = bm + wm + mt * 16 + quad * 4;
#pragma unroll
            for (int r = 0; r < 4; ++r) {
                const long idx = (m0 + r) * N + n;
                const float val = (acc[mt][nt][r] + bv) * scale;
                if (MODE == 1) ((float*)out)[idx] = val + resid[idx];
                else           ((u16*)out)[idx] = f2bf(val);
            }
        }
    }
}

// Fused 6-way gate GEMM + mLSTM gate math.
// A = xadj [M,K], Wcat = 6 gate weights transposed, [6*1024, K] (order
// q,k,v,i,f,o). Block = 128(M) x 32(N) of ALL six projections.
// HALF-TILE staging: 4 rotating half-buffers of 32 K-cols each,
// (128 A-rows + 192 B-rows) x 32 u16 = 20 KB per half, 80 KB total.
// Per phase (one 32-K slice): counted vmcnt -> bar -> 10 ds_read_b128 ->
// lgkm(0) -> bar -> stage half s+3 (5 loads) -> 24 MFMA.
// Wave w owns m-half (w>>1)*64, n-half (w&1)*16. f32 accs, gate math
// in-register, writes ht bf16 [M,1024].
__global__ __launch_bounds__(256) void gemm_gates(
    const u16* __restrict__ A, const u16* __restrict__ Wcat,
    const float* __restrict__ bq_, const float* __restrict__ bk_,
    const float* __restrict__ bv_, const float* __restrict__ bi_,
    const float* __restrict__ bf_, const float* __restrict__ bo_,
    u16* __restrict__ ht, int M, int N, int K)
{
    // half-buffer h (h&3): A rows [0,128) at S + h*10240, B stack rows
    // [0,192) at +4096 u16. Rows are 32 u16 = 64 B.
    __shared__ __align__(16) u16 S[4 * 10240];           // 80 KB

    const int tid  = threadIdx.x;
    const int lane = tid & 63;
    const int wave = tid >> 6;          // 0..3
    const int l15  = lane & 15;
    const int quad = lane >> 4;

    const long bm = (long)blockIdx.y * 128;
    const long bn = (long)blockIdx.x * 32;

    f32x4 acc[6][4] = {};

    // staging: thread tid covers row tid>>2 (+64j); source chunk swizzled
    // so identity LDS placement realizes slot = chunk ^ ((row>>1)&3).
    const int  r0 = tid >> 2;                        // 0..63
    const int  ck = (((tid & 3) ^ ((tid >> 3) & 3)) * 8);
    const u16* gA0 = A + (bm + r0) * (long)K + ck;   // A rows r0, r0+64
    const u16* gB[3];                                // B stack rows r0+64j
#pragma unroll
    for (int j = 0; j < 3; ++j) {
        const int r = r0 + 64 * j;                   // 0..191
        const int g = r >> 5;                        // gate
        gB[j] = Wcat + ((long)g * 1024 + bn + (r & 31)) * (long)K + ck;
    }
    const int ldst = wave * 512;                     // 16 rows x 32 u16

    auto stage = [&](int h) {
        u16* hb = &S[(h & 3) * 10240];
        const long kof = (long)h * 32;
        GLDS16(gA0 + kof, hb + ldst);
        GLDS16(gA0 + kof + 64 * (long)K, hb + ldst + 2048);
        u16* bb = hb + 4096;
        GLDS16(gB[0] + kof, bb + ldst);
        GLDS16(gB[1] + kof, bb + ldst + 2048);
        GLDS16(gB[2] + kof, bb + ldst + 4096);
    };

    const int mh  = (wave >> 1) * 64;                // wave m-half
    const int nb  = (wave & 1) * 16;                 // wave n-half
    const int q8s = (quad ^ ((l15 >> 1) & 3)) * 8;   // swizzled chunk offset
    const int nh  = K >> 5;                          // 32 half-steps

    stage(0); stage(1); stage(2);                    // 15 loads in flight

    for (int s = 0; s < nh; ++s) {
        const int rem = nh - 1 - s;                  // halves still staged after s
        if (rem >= 2)      asm volatile("s_waitcnt vmcnt(10)" ::: "memory");
        else if (rem == 1) asm volatile("s_waitcnt vmcnt(5)"  ::: "memory");
        else               asm volatile("s_waitcnt vmcnt(0)"  ::: "memory");
        __builtin_amdgcn_s_barrier();

        const u16* Ab = &S[(s & 3) * 10240];
        const u16* Bb = Ab + 4096;
        bf16x8 af[4], bfr[6];
#pragma unroll
        for (int t4 = 0; t4 < 4; ++t4)
            af[t4] = *(const bf16x8*)&Ab[(mh + t4 * 16 + l15) * 32 + q8s];
#pragma unroll
        for (int g = 0; g < 6; ++g)
            bfr[g] = *(const bf16x8*)&Bb[(g * 32 + nb + l15) * 32 + q8s];

        asm volatile("s_waitcnt lgkmcnt(0)" ::: "memory");
        __builtin_amdgcn_s_barrier();
        if (s + 3 < nh) stage(s + 3);

#pragma unroll
        for (int g = 0; g < 6; ++g)
#pragma unroll
            for (int t4 = 0; t4 < 4; ++t4)
                acc[g][t4] = __builtin_amdgcn_mfma_f32_16x16x32_bf16(
                    af[t4], bfr[g], acc[g][t4], 0, 0, 0);
    }

    // C/D layout: col = lane&15, row = quad*4 + reg. One n per lane.
    const long n = bn + nb + l15;
    const float bqn = bq_[n], bkn = bk_[n], bvn = bv_[n];
    const float bin = bi_[n], bfn = bf_[n], bon = bo_[n];
#pragma unroll
    for (int t = 0; t < 4; ++t) {
        const long m0 = bm + mh + t * 16 + quad * 4;
#pragma unroll
        for (int r = 0; r < 4; ++r) {
            const float qf = acc[0][t][r] + bqn;
            const float kf = (acc[1][t][r] + bkn) * 0.125f;
            const float vf = acc[2][t][r] + bvn;
            const float fi = acc[3][t][r] + bin;
            const float ff = acc[4][t][r] + bfn;
            const float osig = sigmoidf(acc[5][t][r] + bon);
            const float mx = fmaxf(ff, fi);
            const float fe = __expf(ff - mx);
            const float ct = fe * vf * kf;
            const float h  = osig * (ct * qf) / fmaxf(fabsf(kf * qf), 1.0f);
            ht[(m0 + r) * N + n] = f2bf(h);
        }
    }
}

// LayerNorm over 1024 cols, fp32 in -> bf16 out. One 256-thread block per row.
__global__ __launch_bounds__(256) void ln_in_kernel(
    const float* __restrict__ x, const float* __restrict__ g,
    const float* __restrict__ b, u16* __restrict__ xn)
{
    const long row = blockIdx.x;
    const int  tid = threadIdx.x;
    const float4 v = ((const float4*)(x + row * 1024))[tid];
    float s  = v.x + v.y + v.z + v.w;
    float s2 = v.x * v.x + v.y * v.y + v.z * v.z + v.w * v.w;
#pragma unroll
    for (int off = 32; off > 0; off >>= 1) {
        s  += __shfl_down(s, off);
        s2 += __shfl_down(s2, off);
    }
    __shared__ float red[8];
    const int wave = tid >> 6;
    if ((tid & 63) == 0) { red[wave] = s; red[4 + wave] = s2; }
    __syncthreads();
    if (tid == 0) {
        const float S  = red[0] + red[1] + red[2] + red[3];
        const float S2 = red[4] + red[5] + red[6] + red[7];
        const float mu = S * (1.0f / 1024.0f);
        const float var = S2 * (1.0f / 1024.0f) - mu * mu;
        red[0] = mu; red[1] = rsqrtf(var + 1e-3f);
    }
    __syncthreads();
    const float mu = red[0], rstd = red[1];
    const int c = tid * 4;
    u16x4 o;
    o.x = f2bf((v.x - mu) * rstd * g[c + 0] + b[c + 0]);
    o.y = f2bf((v.y - mu) * rstd * g[c + 1] + b[c + 1]);
    o.z = f2bf((v.z - mu) * rstd * g[c + 2] + b[c + 2]);
    o.w = f2bf((v.w - mu) * rstd * g[c + 3] + b[c + 3]);
    *(u16x4*)(xn + row * 1024 + c) = o;
}

// ---- merged weight-prep (transposes + convert only; bcomb is separate) ---
// Segments by blockIdx.x:
//   [0,2048)       WadjT  transpose, K=2048 N=1024 (x=bid&31, y=bid>>5)
//   [2048,8192)    6 gate transposes -> Wcat, K=N=1024, 1024 tiles each
//   [8192,9216)    WdnT   transpose, K=N=1024
//   [9216,11264)   Wup f32->bf16 linear convert (1024 elems/block)
struct PrepArgs {
    const float *Wadj, *Wq, *Wk, *Wv, *Wi, *Wf, *Wo, *Wdn, *Wup;
    u16 *WadjT, *Wcat, *WdnT, *Wup_bf;
};

__device__ __forceinline__ void do_transpose(
    const float* __restrict__ W, u16* __restrict__ Wt,
    int K, int N, int bx, int by, float (&t)[32][33])
{
    const int tx = threadIdx.x & 31;
    const int ty = threadIdx.x >> 5;
    const long bn = (long)bx * 32;
    const long bk = (long)by * 32;
#pragma unroll
    for (int j = 0; j < 4; ++j)
        t[ty + j * 8][tx] = W[(bk + ty + j * 8) * N + bn + tx];
    __syncthreads();
#pragma unroll
    for (int j = 0; j < 4; ++j)
        Wt[(bn + ty + j * 8) * K + bk + tx] = f2bf(t[tx][ty + j * 8]);
}

__global__ __launch_bounds__(256) void prep_kernel(PrepArgs a)
{
    __shared__ float t[32][33];
    int bid = blockIdx.x;
    if (bid < 2048) {                      // WadjT
        do_transpose(a.Wadj, a.WadjT, 2048, 1024, bid & 31, bid >> 5, t);
        return;
    }
    bid -= 2048;
    if (bid < 6144) {                      // gates -> Wcat (q,k,v,i,f,o)
        const int g = bid >> 10, tt = bid & 1023;
        const float* Wg = g == 0 ? a.Wq : g == 1 ? a.Wk : g == 2 ? a.Wv
                        : g == 3 ? a.Wi : g == 4 ? a.Wf : a.Wo;
        do_transpose(Wg, a.Wcat + (long)g * 1024 * 1024, 1024, 1024,
                     tt & 31, tt >> 5, t);
        return;
    }
    bid -= 6144;
    if (bid < 1024) {                      // WdnT
        do_transpose(a.Wdn, a.WdnT, 1024, 1024, bid & 31, bid >> 5, t);
        return;
    }
    bid -= 1024;
    {                                      // Wup convert (no transpose)
        const long i = ((long)bid * 256 + threadIdx.x) * 4;
        const float4 v = *(const float4*)(a.Wup + i);
        u16x4 o;
        o.x = f2bf(v.x); o.y = f2bf(v.y); o.z = f2bf(v.z); o.w = f2bf(v.w);
        *(u16x4*)(a.Wup_bf + i) = o;
    }
}

// b_comb[h] = dot(WadjT[h,:], b_up) + b_adj[h].  One block per h (parallel).
__global__ __launch_bounds__(256) void bcomb_kernel(
    const u16* __restrict__ WadjT, const float* __restrict__ bup,
    const float* __restrict__ badj, float* __restrict__ bcomb)
{
    const long h = blockIdx.x;
    const int  tid = threadIdx.x;
    const int  p = tid * 8;
    const u16x8 w = *(const u16x8*)&WadjT[h * 2048 + p];
    float s = 0.0f;
#pragma unroll
    for (int j = 0; j < 8; ++j) s += bf2f(w[j]) * bup[p + j];
#pragma unroll
    for (int off = 32; off > 0; off >>= 1) s += __shfl_down(s, off);
    __shared__ float red[4];
    const int wave = tid >> 6;
    if ((tid & 63) == 0) red[wave] = s;
    __syncthreads();
    if (tid == 0)
        bcomb[h] = red[0] + red[1] + red[2] + red[3] + badj[h];
}

// LN2 over ht rows + sigmoid(xadj) product. y may alias ht (same-thread r/w).
__global__ __launch_bounds__(256) void ln2_kernel(
    const u16* __restrict__ ht, const u16* __restrict__ xadj,
    const float* __restrict__ g2, const float* __restrict__ b2,
    u16* __restrict__ y)
{
    const long base = (long)blockIdx.x * 1024;
    const int  tid = threadIdx.x;
    const int  c = tid * 4;
    const u16x4 hv = *(const u16x4*)&ht[base + c];
    const u16x4 xv = *(const u16x4*)&xadj[base + c];

    float h[4];
    float s = 0.0f, s2 = 0.0f;
#pragma unroll
    for (int j = 0; j < 4; ++j) {
        h[j] = bf2f(hv[j]);
        s += h[j]; s2 += h[j] * h[j];
    }
#pragma unroll
    for (int off = 32; off > 0; off >>= 1) {
        s  += __shfl_down(s, off);
        s2 += __shfl_down(s2, off);
    }
    __shared__ float red[8];
    const int wave = tid >> 6;
    if ((tid & 63) == 0) { red[wave] = s; red[4 + wave] = s2; }
    __syncthreads();
    if (tid == 0) {
        const float S  = red[0] + red[1] + red[2] + red[3];
        const float S2 = red[4] + red[5] + red[6] + red[7];
        const float mu = S * (1.0f / 1024.0f);
        const float var = S2 * (1.0f / 1024.0f) - mu * mu;
        red[0] = mu; red[1] = rsqrtf(var + 1e-3f);
    }
    __syncthreads();
    const float mu = red[0], rstd = red[1];
    u16x4 o;
#pragma unroll
    for (int j = 0; j < 4; ++j)
        o[j] = f2bf(((h[j] - mu) * rstd * g2[c + j] + b2[c + j]) * sigmoidf(bf2f(xv[j])));
    *(u16x4*)&y[base + c] = o;
}

extern "C" void kernel_launch(void* const* d_in, const int* in_sizes, int n_in,
                              void* d_out, int out_size, void* d_ws, size_t ws_size,
                              hipStream_t stream)
{
    const float* x    = (const float*)d_in[0];
    const float* g1   = (const float*)d_in[1];
    const float* b1   = (const float*)d_in[2];
    const float* Wup  = (const float*)d_in[3];
    const float* bup  = (const float*)d_in[4];
    const float* Wadj = (const float*)d_in[5];
    const float* badj = (const float*)d_in[6];
    const float* Wq = (const float*)d_in[7];   const float* bq = (const float*)d_in[8];
    const float* Wk = (const float*)d_in[9];   const float* bk = (const float*)d_in[10];
    const float* Wv = (const float*)d_in[11];  const float* bv = (const float*)d_in[12];
    const float* Wi = (const float*)d_in[13];  const float* bi = (const float*)d_in[14];
    const float* Wf = (const float*)d_in[15];  const float* bf = (const float*)d_in[16];
    const float* Wo = (const float*)d_in[17];  const float* bo = (const float*)d_in[18];
    const float* g2 = (const float*)d_in[19];  const float* b2 = (const float*)d_in[20];
    const float* Wdn = (const float*)d_in[21]; const float* bdn = (const float*)d_in[22];

    const int M = 8 * 2048;     // 16384 tokens
    const int D = 1024, P = 2048, H = 1024;

    char* ws = (char*)d_ws;
    const size_t MB = 1024 * 1024;
    u16* xn     = (u16*)(ws + 0);
    u16* htb    = (u16*)(ws + 0);          // reuse xn (dead after xadj-GEMM)
    u16* yb     = (u16*)(ws + 0);          // alias ht (same-thread read-then-write)
    u16* WcombT = (u16*)(ws + 32 * MB);    // [1024,1024] 2MB
    float* bcomb = (float*)(ws + 36 * MB); // f32[1024]
    u16* xadj   = (u16*)(ws + 96 * MB);
    u16* Wup_bf = (u16*)(ws + 128 * MB);   // [1024,2048] row-major 4MB
    u16* WadjT  = (u16*)(ws + 132 * MB);   // [1024,2048] 4MB
    u16* Wcat   = (u16*)(ws + 136 * MB);   // [6*1024,1024] 12MB, q,k,v,i,f,o
    u16* WdnT   = (u16*)(ws + 148 * MB);   // [1024,1024] 2MB -> ends at 150 MiB

    // 1) LN1
    ln_in_kernel<<<M, 256, 0, stream>>>(x, g1, b1, xn);

    // 2) merged transposes + Wup convert
    PrepArgs pa;
    pa.Wadj = Wadj; pa.Wq = Wq; pa.Wk = Wk; pa.Wv = Wv; pa.Wi = Wi;
    pa.Wf = Wf; pa.Wo = Wo; pa.Wdn = Wdn; pa.Wup = Wup;
    pa.WadjT = WadjT; pa.Wcat = Wcat; pa.WdnT = WdnT; pa.Wup_bf = Wup_bf;
    prep_kernel<<<11264, 256, 0, stream>>>(pa);

    // 3) b_comb (parallel, reads WadjT -> after prep)
    bcomb_kernel<<<H, 256, 0, stream>>>(WadjT, bup, badj, bcomb);

    // 4) W_combT = WadjT @ Wup_bf  ([H,P] @ [P,D] -> [H,D], i.e. (Wup@Wadj)^T)
    gemm_bt<2><<<dim3(D / BN, H / BM), 256, 0, stream>>>(
        WadjT, Wup_bf, nullptr, nullptr, WcombT, H, D, P, 1.0f);

    // 5) xadj = xn @ W_comb + b_comb   (folded up+adj projection)
    gemm_bt<0><<<dim3(H / BN, M / BM), 256, 0, stream>>>(
        xn, WcombT, bcomb, nullptr, xadj, M, H, D, 1.0f);

    // 6) fused six-gate GEMM + gate math -> ht (128M x 32N x 6g, half-tiles)
    gemm_gates<<<dim3(H / 32, M / 128), 256, 0, stream>>>(
        xadj, Wcat, bq, bk, bv, bi, bf, bo, htb, M, H, H);

    // 7) LN2 + sigmoid(xadj) -> y
    ln2_kernel<<<M, 256, 0, stream>>>(htb, xadj, g2, b2, yb);

    // 8) down-proj + bias + residual, fp32 out
    gemm_bt<1><<<dim3(D / BN, M / BM), 256, 0, stream>>>(yb, WdnT, bdn, x, (float*)d_out, M, D, H, 1.0f);
}

// Round 6
// 569.573 us; speedup vs baseline: 1.1351x; 1.0195x over previous
//
#include <hip/hip_runtime.h>

// mLSTM block, bf16-MFMA, R10:
//  - gemm_gates REVERTED to the R6/R7 proven structure (BK=64, 2-deep
//    counted-vmcnt, 48 MFMA per barrier-pair; 213us) -- R9's half-tile
//    variant doubled barrier frequency and cut prefetch depth (234us).
//  - NEW: XCD-aware bijective grid swizzle on gemm_gates (T1). Default
//    n-fastest order makes every XCD stream the full 12MB Wcat through its
//    4MB L2 -> B-loads miss to HBM (~900cyc) > 480cyc prefetch cover ->
//    vmcnt stalls (the 45% MfmaUtil ceiling; FETCH 175MB vs 78MB ideal).
//    1-D grid, lin&7 = XCD: XCD x owns n-slices [4x,4x+4), m-major within
//    a slice -> per-XCD B working set = 384KB (L2-resident), xadj goes
//    L3-resident. Predict FETCH -> ~60-90MB, dur -> ~175us.
//  - rest identical to R9 (merged prep, parallel bcomb, no setprio).
// R7 algebraic fold retained: x_adj = x_norm @ (W_up@W_adj) + (b_up@W_adj
// + b_adj); W_combT = WadjT @ Wup via gemm_bt<2>.
// Tokens M = 16384, D = 1024, P = 2048, H = 1024.
//
// LDS swizzle (gemm_bt, rows = 64 B = 4 chunks of 16 B): chunk c of row r
// stored at slot c ^ ((r>>1)&3), via swizzled SOURCE address
// (global_load_lds forces dest = base + lane*16). Readers use
// quad ^ ((l15>>1)&3). Measured 0 conflicts.
//
// gemm_gates swizzle (rows = 128 B = 8 chunks of 16 B): slot = c ^ (r&7);
// staging lane covers row lane>>3, slot lane&7, source chunk
// (lane&7)^(lane>>3). Readers use (ks*4+quad)^(l15&7). Measured 0 conflicts.
//
// Workspace (MiB offsets), total 150 MiB:
//   [0,32)    xn -> ht (xn dead after xadj-GEMM) -> y (same-thread r/w alias)
//   [32,34)   WcombT [1024,1024]
//   [36,36+4K) b_comb (f32[1024])
//   [96,128)  xadj
//   [128,132) Wup_bf [1024,2048] (row-major, no transpose)
//   [132,136) WadjT  [1024,2048]
//   [136,148) Wcat   [6*1024,1024] (order q,k,v,i,f,o)
//   [148,150) WdnT   [1024,1024]

typedef unsigned short u16;
typedef __attribute__((ext_vector_type(4))) unsigned short u16x4;
typedef __attribute__((ext_vector_type(8))) unsigned short u16x8;
typedef __attribute__((ext_vector_type(8))) __bf16 bf16x8;
typedef __attribute__((ext_vector_type(4))) float f32x4;

__device__ __forceinline__ float bf2f(u16 u) {
    union { unsigned int i; float f; } c; c.i = ((unsigned int)u) << 16; return c.f;
}
__device__ __forceinline__ u16 f2bf(float f) {
    union { float f; unsigned int i; } c; c.f = f;
    unsigned int lsb = (c.i >> 16) & 1u;
    c.i += 0x7fffu + lsb;                 // round-to-nearest-even
    return (u16)(c.i >> 16);
}
__device__ __forceinline__ float sigmoidf(float z) {
    return 1.0f / (1.0f + __expf(-z));
}

// async global->LDS, 16B per lane; LDS dest = wave-uniform base + lane*16
#define GLDS16(gp, lp)                                                        \
    __builtin_amdgcn_global_load_lds(                                         \
        (__attribute__((address_space(1))) void*)(void*)(gp),                 \
        (__attribute__((address_space(3))) void*)(lp), 16, 0, 0)

#define BM 128
#define BN 128
#define BK 32

// C[M,N] = A[M,K] @ B[K,N] with Bt = B^T stored [N,K], all bf16, fp32 acc.
// MODE 0: out bf16 = (acc + bias[n]) * scale
// MODE 1: out f32  = (acc + bias[n]) * scale + resid[m*N+n]
// MODE 2: out bf16 = acc * scale              (no bias; bias may be nullptr)
template <int MODE>
__global__ __launch_bounds__(256) void gemm_bt(
    const u16* __restrict__ A, const u16* __restrict__ Bt,
    const float* __restrict__ bias, const float* __restrict__ resid,
    void* __restrict__ out, int M, int N, int K, float scale)
{
    __shared__ __align__(16) u16 As[2 * BM * BK];   // 2 x 8 KB
    __shared__ __align__(16) u16 Bs[2 * BN * BK];   // 2 x 8 KB

    const int tid  = threadIdx.x;
    const int lane = tid & 63;
    const int wave = tid >> 6;
    const int l15  = lane & 15;
    const int quad = lane >> 4;

    const long bm = (long)blockIdx.y * BM;
    const long bn = (long)blockIdx.x * BN;
    const int  wm = (wave >> 1) * 64;   // wave's 64x64 quadrant
    const int  wn = (wave & 1) * 64;

    f32x4 acc[4][4] = {};

    // staging: thread tid covers row tid>>2; SOURCE chunk is swizzled so the
    // identity LDS placement (lane*16) realizes the XOR-swizzled layout.
    const int  r0 = tid >> 2;
    const int  ck = (((tid & 3) ^ ((tid >> 3) & 3)) * 8);
    const u16* ga0 = A  + (bm + r0) * (long)K + ck;
    const u16* gb0 = Bt + (bn + r0) * (long)K + ck;
    const int  ldst = wave * 512;        // wave's dest inside a buffer (u16)

    auto stage = [&](int t_, int b_) {
        const long kof = (long)t_ * BK;
        u16* dA = &As[b_ * (BM * BK) + ldst];
        u16* dB = &Bs[b_ * (BN * BK) + ldst];
        GLDS16(ga0 + kof, dA);
        GLDS16(ga0 + kof + 64 * (long)K, dA + 2048);
        GLDS16(gb0 + kof, dB);
        GLDS16(gb0 + kof + 64 * (long)K, dB + 2048);
    };

    const int q8s = (quad ^ ((l15 >> 1) & 3)) * 8;   // swizzled chunk offset
    const int nk  = K / BK;

    stage(0, 0);    // 4 loads
    stage(1, 1);    // 4 loads -> 8 in flight

    for (int t = 0; t < nk; ++t) {
        const int cur = t & 1;
        if (t + 1 < nk) asm volatile("s_waitcnt vmcnt(4)" ::: "memory");
        else            asm volatile("s_waitcnt vmcnt(0)" ::: "memory");
        __builtin_amdgcn_s_barrier();

        bf16x8 af[4], bfr[4];
#pragma unroll
        for (int t4 = 0; t4 < 4; ++t4) {
            af[t4]  = *(const bf16x8*)&As[cur * (BM * BK) + (wm + t4 * 16 + l15) * BK + q8s];
            bfr[t4] = *(const bf16x8*)&Bs[cur * (BN * BK) + (wn + t4 * 16 + l15) * BK + q8s];
        }
        asm volatile("s_waitcnt lgkmcnt(0)" ::: "memory");
        __builtin_amdgcn_s_barrier();
        if (t + 2 < nk) stage(t + 2, cur);

#pragma unroll
        for (int mt = 0; mt < 4; ++mt)
#pragma unroll
            for (int nt = 0; nt < 4; ++nt)
                acc[mt][nt] = __builtin_amdgcn_mfma_f32_16x16x32_bf16(
                    af[mt], bfr[nt], acc[mt][nt], 0, 0, 0);
    }

    // C/D layout: col = lane&15, row = quad*4 + reg
#pragma unroll
    for (int nt = 0; nt < 4; ++nt) {
        const long n  = bn + wn + nt * 16 + l15;
        const float bv = (MODE == 2) ? 0.0f : bias[n];
#pragma unroll
        for (int mt = 0; mt < 4; ++mt) {
            const long m0 = bm + wm + mt * 16 + quad * 4;
#pragma unroll
            for (int r = 0; r < 4; ++r) {
                const long idx = (m0 + r) * N + n;
                const float val = (acc[mt][nt][r] + bv) * scale;
                if (MODE == 1) ((float*)out)[idx] = val + resid[idx];
                else           ((u16*)out)[idx] = f2bf(val);
            }
        }
    }
}

// Fused 6-way gate GEMM + mLSTM gate math.
// A = xadj [M,K], Wcat = 6 gate weights transposed, [6*1024, K] (order
// q,k,v,i,f,o). Block = 128(M) x 32(N) of ALL six projections, BK=64,
// 256 threads / 4 waves. Wave w owns m-half (w>>1)*64 and n-half (w&1)*16:
// per BK-step 8 A-frag reads + 12 B-frag reads feed 48 MFMAs. f32 accs,
// gate math in-register, writes ht bf16 [M,1024]. 2-deep pipelined.
// 1-D grid + XCD swizzle: lin&7 = XCD (m09); XCD x owns n-blocks
// [x*cn, (x+1)*cn), m-major within a slice -> per-XCD B = 384KB L2-resident.
__global__ __launch_bounds__(256) void gemm_gates(
    const u16* __restrict__ A, const u16* __restrict__ Wcat,
    const float* __restrict__ bq_, const float* __restrict__ bk_,
    const float* __restrict__ bv_, const float* __restrict__ bi_,
    const float* __restrict__ bf_, const float* __restrict__ bo_,
    u16* __restrict__ ht, int M, int N, int K)
{
    __shared__ __align__(16) u16 As[2 * 128 * 64];       // 2 x 16 KB
    __shared__ __align__(16) u16 Bs[2 * 6 * 32 * 64];    // 2 x 24 KB

    const int tid  = threadIdx.x;
    const int lane = tid & 63;
    const int wave = tid >> 6;          // 0..3
    const int l15  = lane & 15;
    const int quad = lane >> 4;

    // ---- XCD-aware bijective swizzle (requires (N/32)%8==0) ----
    const int nmb = M >> 7;                          // m-blocks (128)
    const int cn  = (N >> 5) >> 3;                   // n-blocks per XCD (4)
    const int lin = blockIdx.x;
    const int xcd = lin & 7;
    const int i   = lin >> 3;                        // [0, nmb*cn)
    const long bm = (long)(i % nmb) * 128;
    const long bn = (long)(xcd * cn + i / nmb) * 32;

    f32x4 acc[6][4] = {};

    // ---- staging: 1 KB wave-chunks of 8 rows (rows are 128 B = 64 u16).
    // lane covers row lane>>3 of the chunk, slot lane&7; source chunk is
    // (lane&7)^(lane>>3) so identity LDS placement realizes slot = c^(r&7).
    const int  rr = lane >> 3;                       // row within 8-row group
    const int  ck = (((lane & 7) ^ rr) * 8);         // swizzled source (u16)

    const u16* gaj[4];                               // A: 16 chunks, 4/wave
    int lAo[4];
#pragma unroll
    for (int j = 0; j < 4; ++j) {
        const int c = wave * 4 + j;                  // chunk 0..15
        gaj[j] = A + (bm + c * 8 + rr) * (long)K + ck;
        lAo[j] = c * 512;
    }
    const u16* gbj[6];                               // B: 24 chunks, 6/wave
    int lBo[6];
#pragma unroll
    for (int j = 0; j < 6; ++j) {
        const int c = wave * 6 + j;                  // chunk 0..23
        const int g = c >> 2;                        // gate
        const int r = (c & 3) * 8 + rr;              // row in gate tile 0..31
        gbj[j] = Wcat + ((long)g * 1024 + bn + r) * (long)K + ck;
        lBo[j] = c * 512;
    }

    auto stage = [&](int t_, int b_) {
        const long kof = (long)t_ * 64;
#pragma unroll
        for (int j = 0; j < 4; ++j)
            GLDS16(gaj[j] + kof, &As[b_ * 8192 + lAo[j]]);
#pragma unroll
        for (int j = 0; j < 6; ++j)
            GLDS16(gbj[j] + kof, &Bs[b_ * 12288 + lBo[j]]);
    };

    const int mh = (wave >> 1) * 64;                 // wave m-half
    const int nb = (wave & 1) * 16;                  // wave n-half
    const int l7 = l15 & 7;
    const int nk = K >> 6;                           // 16

    stage(0, 0);    // 10 loads
    stage(1, 1);    // 10 loads -> 20 in flight

    for (int t = 0; t < nk; ++t) {
        const int cur = t & 1;
        if (t + 1 < nk) asm volatile("s_waitcnt vmcnt(10)" ::: "memory");
        else            asm volatile("s_waitcnt vmcnt(0)"  ::: "memory");
        __builtin_amdgcn_s_barrier();

        const int ab = cur * 8192;     // buffer base (u16), mult of 128 B
        const int bb = cur * 12288;

        // ---- ks = 0: read + MFMA (reads complete before 2nd barrier)
        {
            const int so = (quad ^ l7) * 8;
            bf16x8 af[4];
#pragma unroll
            for (int t4 = 0; t4 < 4; ++t4)
                af[t4] = *(const bf16x8*)&As[ab + (mh + t4 * 16 + l15) * 64 + so];
#pragma unroll
            for (int g = 0; g < 6; ++g) {
                const bf16x8 bfrag =
                    *(const bf16x8*)&Bs[bb + (g * 32 + nb + l15) * 64 + so];
#pragma unroll
                for (int t4 = 0; t4 < 4; ++t4)
                    acc[g][t4] = __builtin_amdgcn_mfma_f32_16x16x32_bf16(
                        af[t4], bfrag, acc[g][t4], 0, 0, 0);
            }
        }
        // ---- ks = 1: reads only, then release the buffer
        bf16x8 af1[4], bf1[6];
        {
            const int so = ((4 + quad) ^ l7) * 8;
#pragma unroll
            for (int t4 = 0; t4 < 4; ++t4)
                af1[t4] = *(const bf16x8*)&As[ab + (mh + t4 * 16 + l15) * 64 + so];
#pragma unroll
            for (int g = 0; g < 6; ++g)
                bf1[g] = *(const bf16x8*)&Bs[bb + (g * 32 + nb + l15) * 64 + so];
        }
        asm volatile("s_waitcnt lgkmcnt(0)" ::: "memory");
        __builtin_amdgcn_s_barrier();
        if (t + 2 < nk) stage(t + 2, cur);

        // ---- ks = 1 MFMAs (cover the just-issued loads)
#pragma unroll
        for (int g = 0; g < 6; ++g)
#pragma unroll
            for (int t4 = 0; t4 < 4; ++t4)
                acc[g][t4] = __builtin_amdgcn_mfma_f32_16x16x32_bf16(
                    af1[t4], bf1[g], acc[g][t4], 0, 0, 0);
    }

    // C/D layout: col = lane&15, row = quad*4 + reg. One n per lane.
    const long n = bn + nb + l15;
    const float bqn = bq_[n], bkn = bk_[n], bvn = bv_[n];
    const float bin = bi_[n], bfn = bf_[n], bon = bo_[n];
#pragma unroll
    for (int t = 0; t < 4; ++t) {
        const long m0 = bm + mh + t * 16 + quad * 4;
#pragma unroll
        for (int r = 0; r < 4; ++r) {
            const float qf = acc[0][t][r] + bqn;
            const float kf = (acc[1][t][r] + bkn) * 0.125f;
            const float vf = acc[2][t][r] + bvn;
            const float fi = acc[3][t][r] + bin;
            const float ff = acc[4][t][r] + bfn;
            const float osig = sigmoidf(acc[5][t][r] + bon);
            const float mx = fmaxf(ff, fi);
            const float fe = __expf(ff - mx);
            const float ct = fe * vf * kf;
            const float h  = osig * (ct * qf) / fmaxf(fabsf(kf * qf), 1.0f);
            ht[(m0 + r) * N + n] = f2bf(h);
        }
    }
}

// LayerNorm over 1024 cols, fp32 in -> bf16 out. One 256-thread block per row.
__global__ __launch_bounds__(256) void ln_in_kernel(
    const float* __restrict__ x, const float* __restrict__ g,
    const float* __restrict__ b, u16* __restrict__ xn)
{
    const long row = blockIdx.x;
    const int  tid = threadIdx.x;
    const float4 v = ((const float4*)(x + row * 1024))[tid];
    float s  = v.x + v.y + v.z + v.w;
    float s2 = v.x * v.x + v.y * v.y + v.z * v.z + v.w * v.w;
#pragma unroll
    for (int off = 32; off > 0; off >>= 1) {
        s  += __shfl_down(s, off);
        s2 += __shfl_down(s2, off);
    }
    __shared__ float red[8];
    const int wave = tid >> 6;
    if ((tid & 63) == 0) { red[wave] = s; red[4 + wave] = s2; }
    __syncthreads();
    if (tid == 0) {
        const float S  = red[0] + red[1] + red[2] + red[3];
        const float S2 = red[4] + red[5] + red[6] + red[7];
        const float mu = S * (1.0f / 1024.0f);
        const float var = S2 * (1.0f / 1024.0f) - mu * mu;
        red[0] = mu; red[1] = rsqrtf(var + 1e-3f);
    }
    __syncthreads();
    const float mu = red[0], rstd = red[1];
    const int c = tid * 4;
    u16x4 o;
    o.x = f2bf((v.x - mu) * rstd * g[c + 0] + b[c + 0]);
    o.y = f2bf((v.y - mu) * rstd * g[c + 1] + b[c + 1]);
    o.z = f2bf((v.z - mu) * rstd * g[c + 2] + b[c + 2]);
    o.w = f2bf((v.w - mu) * rstd * g[c + 3] + b[c + 3]);
    *(u16x4*)(xn + row * 1024 + c) = o;
}

// ---- merged weight-prep (transposes + convert only; bcomb is separate) ---
// Segments by blockIdx.x:
//   [0,2048)       WadjT  transpose, K=2048 N=1024 (x=bid&31, y=bid>>5)
//   [2048,8192)    6 gate transposes -> Wcat, K=N=1024, 1024 tiles each
//   [8192,9216)    WdnT   transpose, K=N=1024
//   [9216,11264)   Wup f32->bf16 linear convert (1024 elems/block)
struct PrepArgs {
    const float *Wadj, *Wq, *Wk, *Wv, *Wi, *Wf, *Wo, *Wdn, *Wup;
    u16 *WadjT, *Wcat, *WdnT, *Wup_bf;
};

__device__ __forceinline__ void do_transpose(
    const float* __restrict__ W, u16* __restrict__ Wt,
    int K, int N, int bx, int by, float (&t)[32][33])
{
    const int tx = threadIdx.x & 31;
    const int ty = threadIdx.x >> 5;
    const long bn = (long)bx * 32;
    const long bk = (long)by * 32;
#pragma unroll
    for (int j = 0; j < 4; ++j)
        t[ty + j * 8][tx] = W[(bk + ty + j * 8) * N + bn + tx];
    __syncthreads();
#pragma unroll
    for (int j = 0; j < 4; ++j)
        Wt[(bn + ty + j * 8) * K + bk + tx] = f2bf(t[tx][ty + j * 8]);
}

__global__ __launch_bounds__(256) void prep_kernel(PrepArgs a)
{
    __shared__ float t[32][33];
    int bid = blockIdx.x;
    if (bid < 2048) {                      // WadjT
        do_transpose(a.Wadj, a.WadjT, 2048, 1024, bid & 31, bid >> 5, t);
        return;
    }
    bid -= 2048;
    if (bid < 6144) {                      // gates -> Wcat (q,k,v,i,f,o)
        const int g = bid >> 10, tt = bid & 1023;
        const float* Wg = g == 0 ? a.Wq : g == 1 ? a.Wk : g == 2 ? a.Wv
                        : g == 3 ? a.Wi : g == 4 ? a.Wf : a.Wo;
        do_transpose(Wg, a.Wcat + (long)g * 1024 * 1024, 1024, 1024,
                     tt & 31, tt >> 5, t);
        return;
    }
    bid -= 6144;
    if (bid < 1024) {                      // WdnT
        do_transpose(a.Wdn, a.WdnT, 1024, 1024, bid & 31, bid >> 5, t);
        return;
    }
    bid -= 1024;
    {                                      // Wup convert (no transpose)
        const long i = ((long)bid * 256 + threadIdx.x) * 4;
        const float4 v = *(const float4*)(a.Wup + i);
        u16x4 o;
        o.x = f2bf(v.x); o.y = f2bf(v.y); o.z = f2bf(v.z); o.w = f2bf(v.w);
        *(u16x4*)(a.Wup_bf + i) = o;
    }
}

// b_comb[h] = dot(WadjT[h,:], b_up) + b_adj[h].  One block per h (parallel).
__global__ __launch_bounds__(256) void bcomb_kernel(
    const u16* __restrict__ WadjT, const float* __restrict__ bup,
    const float* __restrict__ badj, float* __restrict__ bcomb)
{
    const long h = blockIdx.x;
    const int  tid = threadIdx.x;
    const int  p = tid * 8;
    const u16x8 w = *(const u16x8*)&WadjT[h * 2048 + p];
    float s = 0.0f;
#pragma unroll
    for (int j = 0; j < 8; ++j) s += bf2f(w[j]) * bup[p + j];
#pragma unroll
    for (int off = 32; off > 0; off >>= 1) s += __shfl_down(s, off);
    __shared__ float red[4];
    const int wave = tid >> 6;
    if ((tid & 63) == 0) red[wave] = s;
    __syncthreads();
    if (tid == 0)
        bcomb[h] = red[0] + red[1] + red[2] + red[3] + badj[h];
}

// LN2 over ht rows + sigmoid(xadj) product. y may alias ht (same-thread r/w).
__global__ __launch_bounds__(256) void ln2_kernel(
    const u16* __restrict__ ht, const u16* __restrict__ xadj,
    const float* __restrict__ g2, const float* __restrict__ b2,
    u16* __restrict__ y)
{
    const long base = (long)blockIdx.x * 1024;
    const int  tid = threadIdx.x;
    const int  c = tid * 4;
    const u16x4 hv = *(const u16x4*)&ht[base + c];
    const u16x4 xv = *(const u16x4*)&xadj[base + c];

    float h[4];
    float s = 0.0f, s2 = 0.0f;
#pragma unroll
    for (int j = 0; j < 4; ++j) {
        h[j] = bf2f(hv[j]);
        s += h[j]; s2 += h[j] * h[j];
    }
#pragma unroll
    for (int off = 32; off > 0; off >>= 1) {
        s  += __shfl_down(s, off);
        s2 += __shfl_down(s2, off);
    }
    __shared__ float red[8];
    const int wave = tid >> 6;
    if ((tid & 63) == 0) { red[wave] = s; red[4 + wave] = s2; }
    __syncthreads();
    if (tid == 0) {
        const float S  = red[0] + red[1] + red[2] + red[3];
        const float S2 = red[4] + red[5] + red[6] + red[7];
        const float mu = S * (1.0f / 1024.0f);
        const float var = S2 * (1.0f / 1024.0f) - mu * mu;
        red[0] = mu; red[1] = rsqrtf(var + 1e-3f);
    }
    __syncthreads();
    const float mu = red[0], rstd = red[1];
    u16x4 o;
#pragma unroll
    for (int j = 0; j < 4; ++j)
        o[j] = f2bf(((h[j] - mu) * rstd * g2[c + j] + b2[c + j]) * sigmoidf(bf2f(xv[j])));
    *(u16x4*)&y[base + c] = o;
}

extern "C" void kernel_launch(void* const* d_in, const int* in_sizes, int n_in,
                              void* d_out, int out_size, void* d_ws, size_t ws_size,
                              hipStream_t stream)
{
    const float* x    = (const float*)d_in[0];
    const float* g1   = (const float*)d_in[1];
    const float* b1   = (const float*)d_in[2];
    const float* Wup  = (const float*)d_in[3];
    const float* bup  = (const float*)d_in[4];
    const float* Wadj = (const float*)d_in[5];
    const float* badj = (const float*)d_in[6];
    const float* Wq = (const float*)d_in[7];   const float* bq = (const float*)d_in[8];
    const float* Wk = (const float*)d_in[9];   const float* bk = (const float*)d_in[10];
    const float* Wv = (const float*)d_in[11];  const float* bv = (const float*)d_in[12];
    const float* Wi = (const float*)d_in[13];  const float* bi = (const float*)d_in[14];
    const float* Wf = (const float*)d_in[15];  const float* bf = (const float*)d_in[16];
    const float* Wo = (const float*)d_in[17];  const float* bo = (const float*)d_in[18];
    const float* g2 = (const float*)d_in[19];  const float* b2 = (const float*)d_in[20];
    const float* Wdn = (const float*)d_in[21]; const float* bdn = (const float*)d_in[22];

    const int M = 8 * 2048;     // 16384 tokens
    const int D = 1024, P = 2048, H = 1024;

    char* ws = (char*)d_ws;
    const size_t MB = 1024 * 1024;
    u16* xn     = (u16*)(ws + 0);
    u16* htb    = (u16*)(ws + 0);          // reuse xn (dead after xadj-GEMM)
    u16* yb     = (u16*)(ws + 0);          // alias ht (same-thread read-then-write)
    u16* WcombT = (u16*)(ws + 32 * MB);    // [1024,1024] 2MB
    float* bcomb = (float*)(ws + 36 * MB); // f32[1024]
    u16* xadj   = (u16*)(ws + 96 * MB);
    u16* Wup_bf = (u16*)(ws + 128 * MB);   // [1024,2048] row-major 4MB
    u16* WadjT  = (u16*)(ws + 132 * MB);   // [1024,2048] 4MB
    u16* Wcat   = (u16*)(ws + 136 * MB);   // [6*1024,1024] 12MB, q,k,v,i,f,o
    u16* WdnT   = (u16*)(ws + 148 * MB);   // [1024,1024] 2MB -> ends at 150 MiB

    // 1) LN1
    ln_in_kernel<<<M, 256, 0, stream>>>(x, g1, b1, xn);

    // 2) merged transposes + Wup convert
    PrepArgs pa;
    pa.Wadj = Wadj; pa.Wq = Wq; pa.Wk = Wk; pa.Wv = Wv; pa.Wi = Wi;
    pa.Wf = Wf; pa.Wo = Wo; pa.Wdn = Wdn; pa.Wup = Wup;
    pa.WadjT = WadjT; pa.Wcat = Wcat; pa.WdnT = WdnT; pa.Wup_bf = Wup_bf;
    prep_kernel<<<11264, 256, 0, stream>>>(pa);

    // 3) b_comb (parallel, reads WadjT -> after prep)
    bcomb_kernel<<<H, 256, 0, stream>>>(WadjT, bup, badj, bcomb);

    // 4) W_combT = WadjT @ Wup_bf  ([H,P] @ [P,D] -> [H,D], i.e. (Wup@Wadj)^T)
    gemm_bt<2><<<dim3(D / BN, H / BM), 256, 0, stream>>>(
        WadjT, Wup_bf, nullptr, nullptr, WcombT, H, D, P, 1.0f);

    // 5) xadj = xn @ W_comb + b_comb   (folded up+adj projection)
    gemm_bt<0><<<dim3(H / BN, M / BM), 256, 0, stream>>>(
        xn, WcombT, bcomb, nullptr, xadj, M, H, D, 1.0f);

    // 6) fused six-gate GEMM + gate math -> ht (1-D grid, XCD swizzle)
    gemm_gates<<<(M / 128) * (H / 32), 256, 0, stream>>>(
        xadj, Wcat, bq, bk, bv, bi, bf, bo, htb, M, H, H);

    // 7) LN2 + sigmoid(xadj) -> y
    ln2_kernel<<<M, 256, 0, stream>>>(htb, xadj, g2, b2, yb);

    // 8) down-proj + bias + residual, fp32 out
    gemm_bt<1><<<dim3(D / BN, M / BM), 256, 0, stream>>>(yb, WdnT, bdn, x, (float*)d_out, M, D, H, 1.0f);
}